// Round 5
// baseline (74.820 us; speedup 1.0000x reference)
//
#include <hip/hip_runtime.h>
#include <hip/hip_bf16.h>

namespace {

constexpr int T_DIM = 16384;   // number of tiles
constexpr int TPW   = 8;       // tiles per wave -> 2048 waves = 512 blocks

typedef __attribute__((ext_vector_type(8))) short bf16x8;
typedef __attribute__((ext_vector_type(4))) float f32x4;

__device__ inline short f2bf(float f) {
    union { __hip_bfloat16 h; short s; } u;
    u.h = __float2bfloat16(f);
    return u.s;
}

__device__ inline bf16x8 cvt8(f32x4 a, f32x4 b) {
    bf16x8 r;
    r[0] = f2bf(a[0]); r[1] = f2bf(a[1]); r[2] = f2bf(a[2]); r[3] = f2bf(a[3]);
    r[4] = f2bf(b[0]); r[5] = f2bf(b[1]); r[6] = f2bf(b[2]); r[7] = f2bf(b[3]);
    return r;
}

} // namespace

// Wave-private streaming: NO LDS, NO barriers. Each wave owns TPW tiles and
// computes all 128 batch rows itself (rf=8), so W1 is read exactly once,
// global->reg, software-pipelined at 4KB (one nf-chunk) granularity with a
// 2-deep register buffer. 2048 independent wave-streams keep ~32KB/CU of
// VMEM in flight with zero barrier coupling (>> the ~9KB BW*latency product).
// The j-reduction (relu-dot) is folded in per-nf so acc is transient.
__global__ __launch_bounds__(256, 2) void fgbn_kernel(
    const float* __restrict__ x,
    const float* __restrict__ W1,
    const float* __restrict__ b1,
    const float* __restrict__ W2,
    const float* __restrict__ b2,
    float* __restrict__ out)
{
    const int lane = threadIdx.x & 63;
    const int wave = threadIdx.x >> 6;
    const int l15  = lane & 15;
    const int l4   = lane >> 4;
    const int wid  = blockIdx.x * 4 + wave;
    const int t0   = wid * TPW;

    // A fragments: all 128 rows of x (every wave computes every row).
    // A[row=lane&15][k=8*(lane>>4)+e], row block rf*16.
    bf16x8 afrag[8][2];   // [rf][ks]
    #pragma unroll
    for (int rf = 0; rf < 8; ++rf) {
        const int row = rf * 16 + l15;
        #pragma unroll
        for (int ks = 0; ks < 2; ++ks) {
            const float* src = x + row * 64 + ks * 32 + l4 * 8;
            afrag[rf][ks] = cvt8(*reinterpret_cast<const f32x4*>(src),
                                 *reinterpret_cast<const f32x4*>(src + 4));
        }
    }

    // One nf-chunk = 16 cols x 64 k of the current W1 tile; per lane 4 f32x4:
    // B[k=8*l4+e][col=nf*16+l15] = W1t[j][k] -> W1 + t*4096 + j*64 + ks*32 + l4*8.
    f32x4 raw[2][4];   // 2-deep pipeline; all indices compile-time (rule #20)
    auto loadchunk = [&](int buf, int t, int nf) {
        const float* base = W1 + (size_t)t * 4096 + (nf * 16 + l15) * 64 + l4 * 8;
        raw[buf][0] = *reinterpret_cast<const f32x4*>(base);
        raw[buf][1] = *reinterpret_cast<const f32x4*>(base + 4);
        raw[buf][2] = *reinterpret_cast<const f32x4*>(base + 32);
        raw[buf][3] = *reinterpret_cast<const f32x4*>(base + 36);
    };

    // Prime the pipeline.
    float b1v[4], w2v[4];
    #pragma unroll
    for (int nf = 0; nf < 4; ++nf) {
        b1v[nf] = b1[t0 * 64 + nf * 16 + l15];
        w2v[nf] = W2[t0 * 64 + nf * 16 + l15];
    }
    float b2v = b2[t0];
    loadchunk(0, t0, 0);

    f32x4 outv[8];
    #pragma unroll
    for (int rf = 0; rf < 8; ++rf) outv[rf] = (f32x4){0.f, 0.f, 0.f, 0.f};

    for (int ti = 0; ti < TPW; ++ti) {
        const int t = t0 + ti;
        const bool more = (ti + 1 < TPW);

        // Prefetch next tile's small vectors (full tile of slack).
        float b1n[4], w2n[4], b2n = 0.f;
        if (more) {
            #pragma unroll
            for (int nf = 0; nf < 4; ++nf) {
                b1n[nf] = b1[(t + 1) * 64 + nf * 16 + l15];
                w2n[nf] = W2[(t + 1) * 64 + nf * 16 + l15];
            }
            b2n = b2[t + 1];
        }

        f32x4 s[8];   // per-lane partial relu-dot, per rf row-quad
        #pragma unroll
        for (int rf = 0; rf < 8; ++rf) s[rf] = (f32x4){0.f, 0.f, 0.f, 0.f};

        #pragma unroll
        for (int nf = 0; nf < 4; ++nf) {
            // Issue next chunk's loads BEFORE consuming the current one; the
            // compiler's counted vmcnt keeps them in flight under the MFMAs.
            if (nf < 3)    loadchunk((nf + 1) & 1, t, nf + 1);
            else if (more) loadchunk(0, t + 1, 0);

            const bf16x8 bks0 = cvt8(raw[nf & 1][0], raw[nf & 1][1]);
            const bf16x8 bks1 = cvt8(raw[nf & 1][2], raw[nf & 1][3]);

            #pragma unroll
            for (int rf = 0; rf < 8; ++rf) {
                f32x4 acc = (f32x4){0.f, 0.f, 0.f, 0.f};
                acc = __builtin_amdgcn_mfma_f32_16x16x32_bf16(afrag[rf][0], bks0, acc, 0, 0, 0);
                acc = __builtin_amdgcn_mfma_f32_16x16x32_bf16(afrag[rf][1], bks1, acc, 0, 0, 0);
                // Fold relu-dot for these 16 j-columns immediately (acc dies here).
                #pragma unroll
                for (int r = 0; r < 4; ++r) {
                    const float p = fmaxf(acc[r] + b1v[nf], 0.f);
                    s[rf][r] = fmaf(p, w2v[nf], s[rf][r]);
                }
            }
        }

        // Butterfly over the 16-lane group -> full j-sum in all lanes;
        // lane l15==ti keeps this tile's result.
        #pragma unroll
        for (int rf = 0; rf < 8; ++rf) {
            #pragma unroll
            for (int r = 0; r < 4; ++r) {
                float v = s[rf][r];
                v += __shfl_xor(v, 1);
                v += __shfl_xor(v, 2);
                v += __shfl_xor(v, 4);
                v += __shfl_xor(v, 8);
                const float y = 2.f * (v + b2v);
                outv[rf][r] = (l15 == ti) ? y : outv[rf][r];
            }
        }

        if (more) {
            #pragma unroll
            for (int nf = 0; nf < 4; ++nf) { b1v[nf] = b1n[nf]; w2v[nf] = w2n[nf]; }
            b2v = b2n;
        }
    }

    // Epilogue: lanes l15=0..7 hold tiles t0..t0+7 -> 32B contiguous stores.
    if (l15 < TPW) {
        #pragma unroll
        for (int rf = 0; rf < 8; ++rf) {
            #pragma unroll
            for (int r = 0; r < 4; ++r) {
                const int brow = rf * 16 + l4 * 4 + r;
                out[(size_t)brow * T_DIM + t0 + l15] = outv[rf][r];
            }
        }
    }
}

extern "C" void kernel_launch(void* const* d_in, const int* in_sizes, int n_in,
                              void* d_out, int out_size, void* d_ws, size_t ws_size,
                              hipStream_t stream) {
    const float* x  = (const float*)d_in[0];
    const float* W1 = (const float*)d_in[1];
    const float* b1 = (const float*)d_in[2];
    const float* W2 = (const float*)d_in[3];
    const float* b2 = (const float*)d_in[4];
    float* out = (float*)d_out;

    dim3 grid(T_DIM / (TPW * 4));   // 512 blocks x 4 waves = 2048 waves
    dim3 block(256);
    hipLaunchKernelGGL(fgbn_kernel, grid, block, 0, stream,
                       x, W1, b1, W2, b2, out);
}